// Round 17
// baseline (60.744 us; speedup 1.0000x reference)
//
#include <hip/hip_runtime.h>
#include <stdint.h>

#define D_M   1024
#define L_OBS 2048
#define ALPHA 8192
#define D_H   2048

typedef __attribute__((ext_vector_type(8))) short short8;
typedef __attribute__((ext_vector_type(4))) float f32x4;

__device__ inline unsigned short f2bf(float f) {
  union { float f; unsigned u; } c; c.f = f;
  unsigned u = c.u;
  u += 0x7fffu + ((u >> 16) & 1u);   // round-to-nearest-even
  return (unsigned short)(u >> 16);
}

// ---------------- Kernel 1: scatter + forward-fill + fused wconv -------------
// blocks [0,1024): one time-series row m (32-bit packed scatter + shuffle scan)
// blocks [1024,2048): W f32 -> bf16 (independent of impute output)
__global__ __launch_bounds__(512) void impute_prep(
    const float* __restrict__ x_ts, const int* __restrict__ t_ts,
    const float* __restrict__ gmean, unsigned short* __restrict__ reg,
    const float* __restrict__ W, unsigned short* __restrict__ Wb) {
  __shared__ unsigned pack[ALPHA];   // 32 KB; 0 = no observation
  __shared__ float s_wv[8];
  __shared__ int   s_wh[8];

  const int tid  = threadIdx.x;

  if (blockIdx.x >= 1024) {          // ---- wconv branch
    const int i = ((blockIdx.x - 1024) * 512 + tid) * 4;
    const float4 w = *reinterpret_cast<const float4*>(&W[i]);
    ushort4 o;
    o.x = f2bf(w.x); o.y = f2bf(w.y); o.z = f2bf(w.z); o.w = f2bf(w.w);
    *reinterpret_cast<ushort4*>(&Wb[i]) = o;
    return;
  }

  const int m    = blockIdx.x;
  const int lane = tid & 63;
  const int wv   = tid >> 6;         // 0..7

  #pragma unroll
  for (int i = 0; i < 4; ++i)
    *reinterpret_cast<uint4*>(&pack[tid * 16 + i * 4]) = make_uint4(0u, 0u, 0u, 0u);
  __syncthreads();

  #pragma unroll
  for (int j = 0; j < 4; ++j) {
    const int l = tid + j * 512;
    const float xv = x_ts[(size_t)m * L_OBS + l];
    const int   tv = t_ts[(size_t)m * L_OBS + l];
    if ((xv == xv) && (tv >= 0) && (tv < ALPHA))
      atomicMax(&pack[tv], ((unsigned)(l + 1) << 16) | (unsigned)f2bf(xv));
  }
  __syncthreads();

  const int base = tid * 16;
  int has = 0; float lv = 0.f;
  #pragma unroll
  for (int i = 0; i < 16; ++i) {
    const unsigned p = pack[base + i];
    if (p >> 16) { has = 1; lv = __uint_as_float(p << 16); }
  }

  int ihas = has; float ilv = lv;
  #pragma unroll
  for (int d = 1; d < 64; d <<= 1) {
    const float pv = __shfl_up(ilv, d, 64);
    const int   ph = __shfl_up(ihas, d, 64);
    if (lane >= d && !ihas) { ihas = ph; ilv = pv; }
  }
  if (lane == 63) { s_wh[wv] = ihas; s_wv[wv] = ilv; }
  __syncthreads();
  if (wv == 0 && lane < 8) {
    int h2 = s_wh[lane]; float v2 = s_wv[lane];
    #pragma unroll
    for (int d = 1; d < 8; d <<= 1) {
      const float pv = __shfl_up(v2, d, 8);
      const int   ph = __shfl_up(h2, d, 8);
      if (lane >= d && !h2) { h2 = ph; v2 = pv; }
    }
    s_wh[lane] = h2; s_wv[lane] = v2;
  }
  __syncthreads();

  const float xlv = __shfl_up(ilv, 1, 64);
  const int   xh_ = __shfl_up(ihas, 1, 64);
  const int   xhas = (lane > 0) ? xh_ : 0;
  float running;
  if (xhas)                         running = xlv;
  else if (wv > 0 && s_wh[wv - 1])  running = s_wv[wv - 1];
  else                              running = gmean[m];

  short8 ov0, ov1;
  #pragma unroll
  for (int i = 0; i < 8; ++i) {
    const unsigned p = pack[base + i];
    if (p >> 16) running = __uint_as_float(p << 16);
    ov0[i] = (short)f2bf(running);
  }
  #pragma unroll
  for (int i = 8; i < 16; ++i) {
    const unsigned p = pack[base + i];
    if (p >> 16) running = __uint_as_float(p << 16);
    ov1[i - 8] = (short)f2bf(running);
  }
  *(short8*)&reg[(size_t)m * ALPHA + base]     = ov0;
  *(short8*)&reg[(size_t)m * ALPHA + base + 8] = ov1;
}

// ---------------- Kernel 1b: transpose reg[m][a] -> regT[a][m] ---------------
__global__ __launch_bounds__(256) void prep(
    const unsigned short* __restrict__ reg, unsigned short* __restrict__ regT) {
  __shared__ unsigned short tile[64 * 64];
  const int t = threadIdx.x;

  const int m0 = (blockIdx.x & 15) * 64;
  const int A0 = (blockIdx.x >> 4) * 64;

  #pragma unroll
  for (int i = 0; i < 2; ++i) {
    const int m  = i * 32 + (t >> 3);
    const int ao = (t & 7) * 8;
    short8 v = *(const short8*)&reg[(size_t)(m0 + m) * ALPHA + A0 + ao];
    const int s = ((m & 7) ^ (m >> 3)) << 3;
    *(short8*)&tile[m * 64 + (ao ^ s)] = v;
  }
  __syncthreads();
  #pragma unroll
  for (int i = 0; i < 2; ++i) {
    const int a  = i * 32 + (t >> 3);
    const int mo = (t & 7) * 8;
    short8 ov;
    #pragma unroll
    for (int j = 0; j < 8; ++j) {
      const int mm = mo + j;
      const int s  = ((mm & 7) ^ (mm >> 3)) << 3;
      ov[j] = (short)tile[mm * 64 + (a ^ s)];
    }
    *(short8*)&regT[(size_t)(A0 + a) * D_M + m0 + mo] = ov;
  }
}

// ---------------- Kernel 3: 128x128 GEMM, BK=64 + NT epilogue stores ---------
// out[a][h] = sum_m regT[a][m] * Wb[h][m] + b[h];  M=8192 N=2048 K=1024.
// R17 change (single variable vs R16): __builtin_nontemporal_store for the
// out epilogue. out (64MB f32, never re-read) streamed through L2 evicts
// the XCD's 4MB B-panel set -> B re-fetched ~7x (FETCH 43MB vs 20MB
// unique). nt stores bypass L2 -> B stays resident across bm iterations.
#define GNT64 16

__device__ inline void gload_lds16(const void* g, void* l) {
  __builtin_amdgcn_global_load_lds(
      (const __attribute__((address_space(1))) unsigned int*)g,
      (__attribute__((address_space(3))) unsigned int*)l, 16, 0, 0);
}

#define BARX() { asm volatile("" ::: "memory"); __builtin_amdgcn_s_barrier(); \
                 asm volatile("" ::: "memory"); }

__global__ __launch_bounds__(512, 4) void gemm_bias(
    const unsigned short* __restrict__ A,   // regT [ALPHA][D_M]
    const unsigned short* __restrict__ B,   // Wb   [D_H][D_M]
    const float* __restrict__ bias, float* __restrict__ out) {
  // slot s: A-half0 @ s*32768, A-half1 @ +8192, B-half0 @ +16384, B-half1 @ +24576
  __shared__ char lds[65536];

  const int tid  = threadIdx.x;
  const int lane = tid & 63;
  const int wid  = tid >> 6;
  const int wm   = wid >> 2;                // 0..1 (64-row half)
  const int wn   = wid & 3;                 // 0..3 (32-col quarter)
  const int xcd  = blockIdx.x & 7;
  const int pos  = blockIdx.x >> 3;         // 0..127
  const int bm   = xcd * 8 + (pos >> 4);    // 0..63 (8 bm per XCD)
  const int bn   = pos & 15;                // 0..15
  const int a0r = bm * 128, h0 = bn * 128;

  f32x4 acc[4][2] = {};
  short8 af[4], bf[2];

  const int r0 = tid >> 2, s0 = tid & 3;    // r0 0..127, 4 chunks per 64B row
  const int swzB = (s0 ^ ((r0 >> 1) & 3)) * 16;
  const char* Asrc = (const char*)A + ((size_t)(a0r + r0) * D_M) * 2 + swzB;
  const char* Bsrc = (const char*)B + ((size_t)(h0 + r0) * D_M) * 2 + swzB;

#define STAGE(S, kt) { \
  char* a_ = lds + (S) * 32768 + tid * 16; \
  gload_lds16(Asrc + (size_t)(kt) * 128,      a_); \
  gload_lds16(Asrc + (size_t)(kt) * 128 + 64, a_ + 8192); \
  char* b_ = lds + (S) * 32768 + 16384 + tid * 16; \
  gload_lds16(Bsrc + (size_t)(kt) * 128,      b_); \
  gload_lds16(Bsrc + (size_t)(kt) * 128 + 64, b_ + 8192); }

  const int rl  = lane & 15;
  const int rsw = ((lane >> 4) ^ ((rl >> 1) & 3)) * 16;
  const int Aro = (wm * 64 + rl) * 64 + rsw;   // + mf*1024, within a half
  const int Bro = (wn * 32 + rl) * 64 + rsw;   // + nf*1024, within a half

#define HALF(S, H) { \
  _Pragma("unroll") \
  for (int mf = 0; mf < 4; ++mf) \
    af[mf] = *(const short8*)(lds + (S) * 32768 + (H) * 8192 + Aro + mf * 1024); \
  _Pragma("unroll") \
  for (int nf = 0; nf < 2; ++nf) \
    bf[nf] = *(const short8*)(lds + (S) * 32768 + 16384 + (H) * 8192 + Bro + nf * 1024); \
  __builtin_amdgcn_s_setprio(1); \
  _Pragma("unroll") \
  for (int mf = 0; mf < 4; ++mf) \
    _Pragma("unroll") \
    for (int nf = 0; nf < 2; ++nf) \
      acc[mf][nf] = __builtin_amdgcn_mfma_f32_16x16x32_bf16(af[mf], bf[nf], acc[mf][nf], 0, 0, 0); \
  __builtin_amdgcn_s_setprio(0); }

#define TILE(S, T) { \
  if ((T) >= 1 && (T) < GNT64 - 1) STAGE(((T) + 1) & 1, (T) + 1); \
  HALF(S, 0); \
  HALF(S, 1); \
  if ((T) < GNT64 - 1) { asm volatile("s_waitcnt vmcnt(0)" ::: "memory"); BARX(); } }

  // prologue: both slots staged (tiles 0,1); slot0 landed, slot1 in flight
  STAGE(0, 0); STAGE(1, 1);
  asm volatile("s_waitcnt vmcnt(4)" ::: "memory");
  BARX();

  for (int tt = 0; tt < GNT64; tt += 2) {
    TILE(0, tt);
    TILE(1, tt + 1);
  }

  // epilogue: C row = (lane>>4)*4 + r (A side), col = lane&15 (B side)
  // NT stores: out is write-once, never re-read -> bypass L2, keep B resident
  const int cl = lane & 15, rq = lane >> 4;
  #pragma unroll
  for (int nf = 0; nf < 2; ++nf) {
    const int h = h0 + wn * 32 + nf * 16 + cl;
    const float bv = bias[h];
    #pragma unroll
    for (int mf = 0; mf < 4; ++mf) {
      const int ar = a0r + wm * 64 + mf * 16 + rq * 4;
      #pragma unroll
      for (int r = 0; r < 4; ++r)
        __builtin_nontemporal_store(acc[mf][nf][r] + bv,
                                    &out[(size_t)(ar + r) * D_H + h]);
    }
  }
#undef STAGE
#undef HALF
#undef TILE
}

// ---------------- fallback-path impute (transposed scattered write) ----------
__global__ __launch_bounds__(512) void impute_fill_t(
    const float* __restrict__ x_ts, const int* __restrict__ t_ts,
    const float* __restrict__ gmean, unsigned short* __restrict__ dst) {
  __shared__ unsigned pack[ALPHA];
  __shared__ float s_wv[8];
  __shared__ int   s_wh[8];

  const int m    = blockIdx.x;
  const int tid  = threadIdx.x;
  const int lane = tid & 63;
  const int wv   = tid >> 6;

  #pragma unroll
  for (int i = 0; i < 4; ++i)
    *reinterpret_cast<uint4*>(&pack[tid * 16 + i * 4]) = make_uint4(0u, 0u, 0u, 0u);
  __syncthreads();

  #pragma unroll
  for (int j = 0; j < 4; ++j) {
    const int l = tid + j * 512;
    const float xv = x_ts[(size_t)m * L_OBS + l];
    const int   tv = t_ts[(size_t)m * L_OBS + l];
    if ((xv == xv) && (tv >= 0) && (tv < ALPHA))
      atomicMax(&pack[tv], ((unsigned)(l + 1) << 16) | (unsigned)f2bf(xv));
  }
  __syncthreads();

  const int base = tid * 16;
  int has = 0; float lv = 0.f;
  #pragma unroll
  for (int i = 0; i < 16; ++i) {
    const unsigned p = pack[base + i];
    if (p >> 16) { has = 1; lv = __uint_as_float(p << 16); }
  }

  int ihas = has; float ilv = lv;
  #pragma unroll
  for (int d = 1; d < 64; d <<= 1) {
    const float pv = __shfl_up(ilv, d, 64);
    const int   ph = __shfl_up(ihas, d, 64);
    if (lane >= d && !ihas) { ihas = ph; ilv = pv; }
  }
  if (lane == 63) { s_wh[wv] = ihas; s_wv[wv] = ilv; }
  __syncthreads();
  if (wv == 0 && lane < 8) {
    int h2 = s_wh[lane]; float v2 = s_wv[lane];
    #pragma unroll
    for (int d = 1; d < 8; d <<= 1) {
      const float pv = __shfl_up(v2, d, 8);
      const int   ph = __shfl_up(h2, d, 8);
      if (lane >= d && !h2) { h2 = ph; v2 = pv; }
    }
    s_wh[lane] = h2; s_wv[lane] = v2;
  }
  __syncthreads();

  const float xlv = __shfl_up(ilv, 1, 64);
  const int   xh_ = __shfl_up(ihas, 1, 64);
  const int   xhas = (lane > 0) ? xh_ : 0;
  float running;
  if (xhas)                         running = xlv;
  else if (wv > 0 && s_wh[wv - 1])  running = s_wv[wv - 1];
  else                              running = gmean[m];

  #pragma unroll
  for (int i = 0; i < 16; ++i) {
    const unsigned p = pack[base + i];
    if (p >> 16) running = __uint_as_float(p << 16);
    dst[(size_t)(base + i) * D_M + m] = f2bf(running);
  }
}

__global__ __launch_bounds__(256) void wconv(const float* __restrict__ W,
                                             unsigned short* __restrict__ Wb) {
  const int i = (blockIdx.x * 256 + threadIdx.x) * 4;
  const float4 w = *reinterpret_cast<const float4*>(&W[i]);
  ushort4 o;
  o.x = f2bf(w.x); o.y = f2bf(w.y); o.z = f2bf(w.z); o.w = f2bf(w.w);
  *reinterpret_cast<ushort4*>(&Wb[i]) = o;
}

extern "C" void kernel_launch(void* const* d_in, const int* in_sizes, int n_in,
                              void* d_out, int out_size, void* d_ws, size_t ws_size,
                              hipStream_t stream) {
  const float* x  = (const float*)d_in[0];
  const int*   t  = (const int*)d_in[1];
  const float* gm = (const float*)d_in[2];
  const float* W  = (const float*)d_in[3];
  const float* b  = (const float*)d_in[4];
  float* out = (float*)d_out;

  const size_t SZ_REG = (size_t)ALPHA * D_M * 2;   // 16 MB
  const size_t SZ_WB  = (size_t)D_H * D_M * 2;     //  4 MB
  const int GRID = (ALPHA / 128) * (D_H / 128);    // 1024

  if (ws_size >= 2 * SZ_REG + SZ_WB) {
    unsigned short* reg  = (unsigned short*)d_ws;
    unsigned short* regT = (unsigned short*)((char*)d_ws + SZ_REG);
    unsigned short* Wb   = (unsigned short*)((char*)d_ws + 2 * SZ_REG);
    impute_prep<<<2048, 512, 0, stream>>>(x, t, gm, reg, W, Wb);
    prep<<<(ALPHA / 64) * (D_M / 64), 256, 0, stream>>>(reg, regT);
    gemm_bias<<<GRID, 512, 0, stream>>>(regT, Wb, b, out);
  } else {
    unsigned short* regT = (unsigned short*)d_ws;
    unsigned short* Wb   = (unsigned short*)((char*)d_ws + SZ_REG);
    impute_fill_t<<<D_M, 512, 0, stream>>>(x, t, gm, regT);
    wconv<<<(D_H * D_M) / 1024, 256, 0, stream>>>(W, Wb);
    gemm_bias<<<GRID, 512, 0, stream>>>(regT, Wb, b, out);
  }
}

// Round 18
// 59.244 us; speedup vs baseline: 1.0253x; 1.0253x over previous
//
#include <hip/hip_runtime.h>
#include <stdint.h>

#define D_M   1024
#define L_OBS 2048
#define ALPHA 8192
#define D_H   2048

typedef __attribute__((ext_vector_type(8))) short short8;
typedef __attribute__((ext_vector_type(4))) float f32x4;

__device__ inline unsigned short f2bf(float f) {
  union { float f; unsigned u; } c; c.f = f;
  unsigned u = c.u;
  u += 0x7fffu + ((u >> 16) & 1u);   // round-to-nearest-even
  return (unsigned short)(u >> 16);
}

// ---------------- Kernel 1: scatter + forward-fill + fused wconv -------------
// blocks [0,1024): one time-series row m (32-bit packed scatter + shuffle scan)
// blocks [1024,2048): W f32 -> bf16 (independent of impute output)
__global__ __launch_bounds__(512) void impute_prep(
    const float* __restrict__ x_ts, const int* __restrict__ t_ts,
    const float* __restrict__ gmean, unsigned short* __restrict__ reg,
    const float* __restrict__ W, unsigned short* __restrict__ Wb) {
  __shared__ unsigned pack[ALPHA];   // 32 KB; 0 = no observation
  __shared__ float s_wv[8];
  __shared__ int   s_wh[8];

  const int tid  = threadIdx.x;

  if (blockIdx.x >= 1024) {          // ---- wconv branch
    const int i = ((blockIdx.x - 1024) * 512 + tid) * 4;
    const float4 w = *reinterpret_cast<const float4*>(&W[i]);
    ushort4 o;
    o.x = f2bf(w.x); o.y = f2bf(w.y); o.z = f2bf(w.z); o.w = f2bf(w.w);
    *reinterpret_cast<ushort4*>(&Wb[i]) = o;
    return;
  }

  const int m    = blockIdx.x;
  const int lane = tid & 63;
  const int wv   = tid >> 6;         // 0..7

  #pragma unroll
  for (int i = 0; i < 4; ++i)
    *reinterpret_cast<uint4*>(&pack[tid * 16 + i * 4]) = make_uint4(0u, 0u, 0u, 0u);
  __syncthreads();

  #pragma unroll
  for (int j = 0; j < 4; ++j) {
    const int l = tid + j * 512;
    const float xv = x_ts[(size_t)m * L_OBS + l];
    const int   tv = t_ts[(size_t)m * L_OBS + l];
    if ((xv == xv) && (tv >= 0) && (tv < ALPHA))
      atomicMax(&pack[tv], ((unsigned)(l + 1) << 16) | (unsigned)f2bf(xv));
  }
  __syncthreads();

  const int base = tid * 16;
  int has = 0; float lv = 0.f;
  #pragma unroll
  for (int i = 0; i < 16; ++i) {
    const unsigned p = pack[base + i];
    if (p >> 16) { has = 1; lv = __uint_as_float(p << 16); }
  }

  int ihas = has; float ilv = lv;
  #pragma unroll
  for (int d = 1; d < 64; d <<= 1) {
    const float pv = __shfl_up(ilv, d, 64);
    const int   ph = __shfl_up(ihas, d, 64);
    if (lane >= d && !ihas) { ihas = ph; ilv = pv; }
  }
  if (lane == 63) { s_wh[wv] = ihas; s_wv[wv] = ilv; }
  __syncthreads();
  if (wv == 0 && lane < 8) {
    int h2 = s_wh[lane]; float v2 = s_wv[lane];
    #pragma unroll
    for (int d = 1; d < 8; d <<= 1) {
      const float pv = __shfl_up(v2, d, 8);
      const int   ph = __shfl_up(h2, d, 8);
      if (lane >= d && !h2) { h2 = ph; v2 = pv; }
    }
    s_wh[lane] = h2; s_wv[lane] = v2;
  }
  __syncthreads();

  const float xlv = __shfl_up(ilv, 1, 64);
  const int   xh_ = __shfl_up(ihas, 1, 64);
  const int   xhas = (lane > 0) ? xh_ : 0;
  float running;
  if (xhas)                         running = xlv;
  else if (wv > 0 && s_wh[wv - 1])  running = s_wv[wv - 1];
  else                              running = gmean[m];

  short8 ov0, ov1;
  #pragma unroll
  for (int i = 0; i < 8; ++i) {
    const unsigned p = pack[base + i];
    if (p >> 16) running = __uint_as_float(p << 16);
    ov0[i] = (short)f2bf(running);
  }
  #pragma unroll
  for (int i = 8; i < 16; ++i) {
    const unsigned p = pack[base + i];
    if (p >> 16) running = __uint_as_float(p << 16);
    ov1[i - 8] = (short)f2bf(running);
  }
  *(short8*)&reg[(size_t)m * ALPHA + base]     = ov0;
  *(short8*)&reg[(size_t)m * ALPHA + base + 8] = ov1;
}

// ---------------- Kernel 1b: transpose reg[m][a] -> regT[a][m] ---------------
__global__ __launch_bounds__(256) void prep(
    const unsigned short* __restrict__ reg, unsigned short* __restrict__ regT) {
  __shared__ unsigned short tile[64 * 64];
  const int t = threadIdx.x;

  const int m0 = (blockIdx.x & 15) * 64;
  const int A0 = (blockIdx.x >> 4) * 64;

  #pragma unroll
  for (int i = 0; i < 2; ++i) {
    const int m  = i * 32 + (t >> 3);
    const int ao = (t & 7) * 8;
    short8 v = *(const short8*)&reg[(size_t)(m0 + m) * ALPHA + A0 + ao];
    const int s = ((m & 7) ^ (m >> 3)) << 3;
    *(short8*)&tile[m * 64 + (ao ^ s)] = v;
  }
  __syncthreads();
  #pragma unroll
  for (int i = 0; i < 2; ++i) {
    const int a  = i * 32 + (t >> 3);
    const int mo = (t & 7) * 8;
    short8 ov;
    #pragma unroll
    for (int j = 0; j < 8; ++j) {
      const int mm = mo + j;
      const int s  = ((mm & 7) ^ (mm >> 3)) << 3;
      ov[j] = (short)tile[mm * 64 + (a ^ s)];
    }
    *(short8*)&regT[(size_t)(A0 + a) * D_M + m0 + mo] = ov;
  }
}

// ---------------- Kernel 3: 128x128 GEMM, BK=64 (R14/R16 verified best) ------
// out[a][h] = sum_m regT[a][m] * Wb[h][m] + b[h];  M=8192 N=2048 K=1024.
// 16 K-tiles, 16 sync events; each K-half an R8-style [128][32] half-tile
// (64B rows, 0-conflict swizzle pair, b128 reads). LDS 2 x 32KB -> 2 blk/CU,
// 16 waves/CU. A-partitioned XCD map (A fetched once chip-wide). Plain
// epilogue stores (R17 NT-store experiment regressed: WRITE 69->80MB).
#define GNT64 16

__device__ inline void gload_lds16(const void* g, void* l) {
  __builtin_amdgcn_global_load_lds(
      (const __attribute__((address_space(1))) unsigned int*)g,
      (__attribute__((address_space(3))) unsigned int*)l, 16, 0, 0);
}

#define BARX() { asm volatile("" ::: "memory"); __builtin_amdgcn_s_barrier(); \
                 asm volatile("" ::: "memory"); }

__global__ __launch_bounds__(512, 4) void gemm_bias(
    const unsigned short* __restrict__ A,   // regT [ALPHA][D_M]
    const unsigned short* __restrict__ B,   // Wb   [D_H][D_M]
    const float* __restrict__ bias, float* __restrict__ out) {
  // slot s: A-half0 @ s*32768, A-half1 @ +8192, B-half0 @ +16384, B-half1 @ +24576
  __shared__ char lds[65536];

  const int tid  = threadIdx.x;
  const int lane = tid & 63;
  const int wid  = tid >> 6;
  const int wm   = wid >> 2;                // 0..1 (64-row half)
  const int wn   = wid & 3;                 // 0..3 (32-col quarter)
  const int xcd  = blockIdx.x & 7;
  const int pos  = blockIdx.x >> 3;         // 0..127
  const int bm   = xcd * 8 + (pos >> 4);    // 0..63 (8 bm per XCD)
  const int bn   = pos & 15;                // 0..15
  const int a0r = bm * 128, h0 = bn * 128;

  f32x4 acc[4][2] = {};
  short8 af[4], bf[2];

  const int r0 = tid >> 2, s0 = tid & 3;    // r0 0..127, 4 chunks per 64B row
  const int swzB = (s0 ^ ((r0 >> 1) & 3)) * 16;
  const char* Asrc = (const char*)A + ((size_t)(a0r + r0) * D_M) * 2 + swzB;
  const char* Bsrc = (const char*)B + ((size_t)(h0 + r0) * D_M) * 2 + swzB;

#define STAGE(S, kt) { \
  char* a_ = lds + (S) * 32768 + tid * 16; \
  gload_lds16(Asrc + (size_t)(kt) * 128,      a_); \
  gload_lds16(Asrc + (size_t)(kt) * 128 + 64, a_ + 8192); \
  char* b_ = lds + (S) * 32768 + 16384 + tid * 16; \
  gload_lds16(Bsrc + (size_t)(kt) * 128,      b_); \
  gload_lds16(Bsrc + (size_t)(kt) * 128 + 64, b_ + 8192); }

  const int rl  = lane & 15;
  const int rsw = ((lane >> 4) ^ ((rl >> 1) & 3)) * 16;
  const int Aro = (wm * 64 + rl) * 64 + rsw;   // + mf*1024, within a half
  const int Bro = (wn * 32 + rl) * 64 + rsw;   // + nf*1024, within a half

#define HALF(S, H) { \
  _Pragma("unroll") \
  for (int mf = 0; mf < 4; ++mf) \
    af[mf] = *(const short8*)(lds + (S) * 32768 + (H) * 8192 + Aro + mf * 1024); \
  _Pragma("unroll") \
  for (int nf = 0; nf < 2; ++nf) \
    bf[nf] = *(const short8*)(lds + (S) * 32768 + 16384 + (H) * 8192 + Bro + nf * 1024); \
  __builtin_amdgcn_s_setprio(1); \
  _Pragma("unroll") \
  for (int mf = 0; mf < 4; ++mf) \
    _Pragma("unroll") \
    for (int nf = 0; nf < 2; ++nf) \
      acc[mf][nf] = __builtin_amdgcn_mfma_f32_16x16x32_bf16(af[mf], bf[nf], acc[mf][nf], 0, 0, 0); \
  __builtin_amdgcn_s_setprio(0); }

#define TILE(S, T) { \
  if ((T) >= 1 && (T) < GNT64 - 1) STAGE(((T) + 1) & 1, (T) + 1); \
  HALF(S, 0); \
  HALF(S, 1); \
  if ((T) < GNT64 - 1) { asm volatile("s_waitcnt vmcnt(0)" ::: "memory"); BARX(); } }

  // prologue: both slots staged (tiles 0,1); slot0 landed, slot1 in flight
  STAGE(0, 0); STAGE(1, 1);
  asm volatile("s_waitcnt vmcnt(4)" ::: "memory");
  BARX();

  for (int tt = 0; tt < GNT64; tt += 2) {
    TILE(0, tt);
    TILE(1, tt + 1);
  }

  // epilogue: C row = (lane>>4)*4 + r (A side), col = lane&15 (B side)
  const int cl = lane & 15, rq = lane >> 4;
  #pragma unroll
  for (int nf = 0; nf < 2; ++nf) {
    const int h = h0 + wn * 32 + nf * 16 + cl;
    const float bv = bias[h];
    #pragma unroll
    for (int mf = 0; mf < 4; ++mf) {
      const int ar = a0r + wm * 64 + mf * 16 + rq * 4;
      #pragma unroll
      for (int r = 0; r < 4; ++r)
        out[(size_t)(ar + r) * D_H + h] = acc[mf][nf][r] + bv;
    }
  }
#undef STAGE
#undef HALF
#undef TILE
}

// ---------------- fallback-path impute (transposed scattered write) ----------
__global__ __launch_bounds__(512) void impute_fill_t(
    const float* __restrict__ x_ts, const int* __restrict__ t_ts,
    const float* __restrict__ gmean, unsigned short* __restrict__ dst) {
  __shared__ unsigned pack[ALPHA];
  __shared__ float s_wv[8];
  __shared__ int   s_wh[8];

  const int m    = blockIdx.x;
  const int tid  = threadIdx.x;
  const int lane = tid & 63;
  const int wv   = tid >> 6;

  #pragma unroll
  for (int i = 0; i < 4; ++i)
    *reinterpret_cast<uint4*>(&pack[tid * 16 + i * 4]) = make_uint4(0u, 0u, 0u, 0u);
  __syncthreads();

  #pragma unroll
  for (int j = 0; j < 4; ++j) {
    const int l = tid + j * 512;
    const float xv = x_ts[(size_t)m * L_OBS + l];
    const int   tv = t_ts[(size_t)m * L_OBS + l];
    if ((xv == xv) && (tv >= 0) && (tv < ALPHA))
      atomicMax(&pack[tv], ((unsigned)(l + 1) << 16) | (unsigned)f2bf(xv));
  }
  __syncthreads();

  const int base = tid * 16;
  int has = 0; float lv = 0.f;
  #pragma unroll
  for (int i = 0; i < 16; ++i) {
    const unsigned p = pack[base + i];
    if (p >> 16) { has = 1; lv = __uint_as_float(p << 16); }
  }

  int ihas = has; float ilv = lv;
  #pragma unroll
  for (int d = 1; d < 64; d <<= 1) {
    const float pv = __shfl_up(ilv, d, 64);
    const int   ph = __shfl_up(ihas, d, 64);
    if (lane >= d && !ihas) { ihas = ph; ilv = pv; }
  }
  if (lane == 63) { s_wh[wv] = ihas; s_wv[wv] = ilv; }
  __syncthreads();
  if (wv == 0 && lane < 8) {
    int h2 = s_wh[lane]; float v2 = s_wv[lane];
    #pragma unroll
    for (int d = 1; d < 8; d <<= 1) {
      const float pv = __shfl_up(v2, d, 8);
      const int   ph = __shfl_up(h2, d, 8);
      if (lane >= d && !h2) { h2 = ph; v2 = pv; }
    }
    s_wh[lane] = h2; s_wv[lane] = v2;
  }
  __syncthreads();

  const float xlv = __shfl_up(ilv, 1, 64);
  const int   xh_ = __shfl_up(ihas, 1, 64);
  const int   xhas = (lane > 0) ? xh_ : 0;
  float running;
  if (xhas)                         running = xlv;
  else if (wv > 0 && s_wh[wv - 1])  running = s_wv[wv - 1];
  else                              running = gmean[m];

  #pragma unroll
  for (int i = 0; i < 16; ++i) {
    const unsigned p = pack[base + i];
    if (p >> 16) running = __uint_as_float(p << 16);
    dst[(size_t)(base + i) * D_M + m] = f2bf(running);
  }
}

__global__ __launch_bounds__(256) void wconv(const float* __restrict__ W,
                                             unsigned short* __restrict__ Wb) {
  const int i = (blockIdx.x * 256 + threadIdx.x) * 4;
  const float4 w = *reinterpret_cast<const float4*>(&W[i]);
  ushort4 o;
  o.x = f2bf(w.x); o.y = f2bf(w.y); o.z = f2bf(w.z); o.w = f2bf(w.w);
  *reinterpret_cast<ushort4*>(&Wb[i]) = o;
}

extern "C" void kernel_launch(void* const* d_in, const int* in_sizes, int n_in,
                              void* d_out, int out_size, void* d_ws, size_t ws_size,
                              hipStream_t stream) {
  const float* x  = (const float*)d_in[0];
  const int*   t  = (const int*)d_in[1];
  const float* gm = (const float*)d_in[2];
  const float* W  = (const float*)d_in[3];
  const float* b  = (const float*)d_in[4];
  float* out = (float*)d_out;

  const size_t SZ_REG = (size_t)ALPHA * D_M * 2;   // 16 MB
  const size_t SZ_WB  = (size_t)D_H * D_M * 2;     //  4 MB
  const int GRID = (ALPHA / 128) * (D_H / 128);    // 1024

  if (ws_size >= 2 * SZ_REG + SZ_WB) {
    unsigned short* reg  = (unsigned short*)d_ws;
    unsigned short* regT = (unsigned short*)((char*)d_ws + SZ_REG);
    unsigned short* Wb   = (unsigned short*)((char*)d_ws + 2 * SZ_REG);
    impute_prep<<<2048, 512, 0, stream>>>(x, t, gm, reg, W, Wb);
    prep<<<(ALPHA / 64) * (D_M / 64), 256, 0, stream>>>(reg, regT);
    gemm_bias<<<GRID, 512, 0, stream>>>(regT, Wb, b, out);
  } else {
    unsigned short* regT = (unsigned short*)d_ws;
    unsigned short* Wb   = (unsigned short*)((char*)d_ws + SZ_REG);
    impute_fill_t<<<D_M, 512, 0, stream>>>(x, t, gm, regT);
    wconv<<<(D_H * D_M) / 1024, 256, 0, stream>>>(W, Wb);
    gemm_bias<<<GRID, 512, 0, stream>>>(regT, Wb, b, out);
  }
}